// Round 9
// baseline (189.317 us; speedup 1.0000x reference)
//
#include <hip/hip_runtime.h>
#include <math.h>

#define CIN    64
#define OUTC   64
#define BOT    16
#define KK     9
#define HH     48
#define WW     48
#define LPIX   (HH*WW)
#define WSZ    9216
#define PSZ    1024
#define PREDCH 10304
#define GRPSZ  2576
#define BATCH  2
#define NPX    8           // 2 rows x 4 cols of pixels per block
#define PXS2   1172        // px-stride (ushorts): c-stride 18 (16 d + 2 pad)
#define XTS    25          // xt per-c stride (floats): 4x6 window + 1 pad
#define DBS    65

typedef __attribute__((ext_vector_type(8))) short short8v;
typedef __attribute__((ext_vector_type(4))) float float4v;

__device__ inline unsigned short f2bf(float f){
    unsigned u = __float_as_uint(f);
    return (unsigned short)((u + 0x7FFFu + ((u>>16)&1u)) >> 16);   // RNE
}
// truncating pack of two fp32 -> (bf16(hi)<<16)|bf16(lo)
__device__ inline unsigned pk2bf(float lo, float hi){
    return (__float_as_uint(lo) >> 16) | (__float_as_uint(hi) & 0xFFFF0000u);
}

// Block = 8 px (2x4), 512 threads (8 waves), grid 576 (~2.25/CU).
// LDS ~46 KB, VGPR <= 128 (launch_bounds 512,4) -> 2 blocks (16 waves) resident:
// pred (VALU/VMEM) of one block overlaps Y (MFMA/LDS) of the other.
// Wp is read fp32 and truncate-packed to bf16 inline -> no pre-kernel, no d_ws.
__global__ __launch_bounds__(512, 4) void dppc9(
    const float* __restrict__ x,
    const float* __restrict__ Wp,
    const float* __restrict__ bp,
    float* __restrict__ out)
{
    __shared__ float          xt[64 * XTS];         //  6400 B  [c][r4][c6]
    __shared__ unsigned short S[2][NPX * PXS2];     // 37504 B  P_t dbuf; S[0] also stages Q
    __shared__ float          dynb[NPX * DBS];      //  2080 B

    const int tid  = threadIdx.x;
    const int wave = tid >> 6;
    const int lane = tid & 63;
    const int quad = lane >> 4;
    const int lrow = lane & 15;

    const int bi = blockIdx.x;
    const int b  = bi / 288;           // 288 tiles per image (24 x 12)
    const int r  = bi - b * 288;
    const int h0 = (r / 12) * 2;
    const int w0 = (r - 12 * (r / 12)) * 4;

    // ---- xt load: rows h0-1..h0+2, cols w0-1..w0+4, zero-padded ----
    const float* xb = x + (size_t)b * CIN * LPIX;
    for (int i = tid; i < 64 * 24; i += 512) {
        const int c  = i / 24;
        const int rm = i - c * 24;
        const int hi = h0 - 1 + rm / 6;
        const int wi = w0 - 1 + rm % 6;
        float v = 0.0f;
        if (hi >= 0 && hi < HH && wi >= 0 && wi < WW)
            v = xb[c * LPIX + hi * WW + wi];
        xt[c * XTS + rm] = v;
    }
    __syncthreads();

    const float4* Wp4 = (const float4*)Wp;

    // ---- pred B-frag from center x (t-independent); n = lrow = px ----
    short8v Bf[4];
    #pragma unroll
    for (int g = 0; g < 4; ++g) {
        const int px = lrow;
        short8v f = (short8v)0;
        if (quad < 2 && px < NPX) {
            const int pr = px >> 2, pc = px & 3;
            #pragma unroll
            for (int j = 0; j < 8; ++j)
                f[j] = (short)f2bf(xt[(g * 16 + quad * 8 + j) * XTS + (pr + 1) * 6 + pc + 1]);
        }
        if (quad == 2 && lrow < NPX) f[0] = (short)0x3F80;   // bf16(1.0) bias slot
        Bf[g] = f;
    }

    // ---- load one Wp row (fp32) as bf16 A-frag halves ----
    #define LOAD_A(MYCH)                                                              \
        short8v a = (short8v)0;                                                       \
        if (quad < 2) {                                                               \
            const float4 wa = Wp4[(size_t)(MYCH) * 4 + quad * 2];                     \
            const float4 wb = Wp4[(size_t)(MYCH) * 4 + quad * 2 + 1];                 \
            union { short8v s; uint4 u; } av;                                         \
            av.u.x = pk2bf(wa.x, wa.y); av.u.y = pk2bf(wa.z, wa.w);                   \
            av.u.z = pk2bf(wb.x, wb.y); av.u.w = pk2bf(wb.z, wb.w);                   \
            a = av.s;                                                                 \
        } else if (quad == 2) a[0] = (short)f2bf(bp[MYCH]);

    // ---- Q + dyn_b phase (group 3), Q -> S[0] as [px][o*18+j] ----
    for (int u = wave; u < 68; u += 8) {
        const int ch0  = WSZ + u * 16;
        const int mych = ch0 + lrow;
        LOAD_A(mych)
        float4v Dv = {0.f, 0.f, 0.f, 0.f};
        Dv = __builtin_amdgcn_mfma_f32_16x16x32_bf16(a, Bf[3], Dv, 0, 0, 0);
        const int px = lrow;
        if (px < NPX) {
            #pragma unroll
            for (int rr = 0; rr < 4; ++rr) {
                const int ch = ch0 + quad * 4 + rr;
                if (ch < WSZ + PSZ) {
                    const int i = ch - WSZ;
                    S[0][px * PXS2 + (i >> 4) * 18 + (i & 15)] = f2bf(Dv[rr]);
                } else {
                    dynb[px * DBS + (ch - WSZ - PSZ)] = Dv[rr];
                }
            }
        }
    }
    __syncthreads();

    // ---- cache Q B-frags in registers: this wave's pixel (px = wave) ----
    const int pxA = wave;              // 0..7
    short8v Bq[4];
    #pragma unroll
    for (int Nt = 0; Nt < 4; ++Nt) {
        short8v f = (short8v)0;
        if (quad < 2)
            f = *(const short8v*)&S[0][pxA * PXS2 + (Nt * 16 + lrow) * 18 + quad * 8];
        Bq[Nt] = f;
    }
    __syncthreads();   // all waves done reading S[0] before pred(0) overwrites it

    float acc[4] = {};

    // ---- pred slice for tap t into buf (STATIC Bf indices) ----
    #define PASS(GG)                                                                  \
        { short8v am = (myg == (GG)) ? a : (short8v)0;                                \
          Dv = __builtin_amdgcn_mfma_f32_16x16x32_bf16(am, Bf[GG], Dv, 0, 0, 0); }

    #define PRED_SLICE(T, BUF)                                                        \
    for (int u = wave; u < 64; u += 8) {                                              \
        const int d  = u >> 2;                                                        \
        const int c0 = (u & 3) * 16;                                                  \
        const int ch0  = d * 576 + c0 * 9 + (T);                                      \
        const int mych = ch0 + 9 * lrow;                                              \
        LOAD_A(mych)                                                                  \
        const int g0  = ch0 / GRPSZ;                                                  \
        const int g1  = (ch0 + 135) / GRPSZ;                                          \
        const int myg = mych / GRPSZ;                                                 \
        float4v Dv = {0.f, 0.f, 0.f, 0.f};                                            \
        if (g0 == 0)      { PASS(0) if (g1 == 1) PASS(1) }                            \
        else if (g0 == 1) { PASS(1) if (g1 == 2) PASS(2) }                            \
        else if (g0 == 2) { PASS(2) if (g1 == 3) PASS(3) }                            \
        else              { PASS(3) }                                                 \
        const int px = lrow;                                                          \
        if (px < NPX) {                                                               \
            _Pragma("unroll")                                                         \
            for (int rr = 0; rr < 4; ++rr)                                            \
                S[BUF][px * PXS2 + (c0 + quad * 4 + rr) * 18 + d] = f2bf(Dv[rr]);     \
        }                                                                             \
    }

    PRED_SLICE(0, 0)
    __syncthreads();

    for (int t = 0; t < KK; ++t) {
        const int buf = t & 1;
        if (t < 8) { PRED_SLICE(t + 1, (t + 1) & 1) }

        // ---- Y = P_t^T Q for this wave's pixel ----
        const int tr = t / 3, tc = t - 3 * (t / 3);
        const int pr = pxA >> 2, pc = pxA & 3;

        short8v Ap[4];
        #pragma unroll
        for (int Mt = 0; Mt < 4; ++Mt) {
            short8v f = (short8v)0;
            if (quad < 2)
                f = *(const short8v*)&S[buf][pxA * PXS2 + (Mt * 16 + lrow) * 18 + quad * 8];
            Ap[Mt] = f;
        }
        float pv[4][4];
        #pragma unroll
        for (int Mt = 0; Mt < 4; ++Mt)
            #pragma unroll
            for (int rr = 0; rr < 4; ++rr) {
                const int c = Mt * 16 + quad * 4 + rr;
                pv[Mt][rr] = xt[c * XTS + (pr + tr) * 6 + pc + tc];
            }

        #pragma unroll
        for (int Nt = 0; Nt < 4; ++Nt) {
            float nacc = 0.f, dpacc = 0.f;
            #pragma unroll
            for (int Mt = 0; Mt < 4; ++Mt) {
                float4v Dv = {0.f, 0.f, 0.f, 0.f};
                Dv = __builtin_amdgcn_mfma_f32_16x16x32_bf16(Ap[Mt], Bq[Nt], Dv, 0, 0, 0);
                #pragma unroll
                for (int rr = 0; rr < 4; ++rr) {
                    nacc  += Dv[rr] * Dv[rr];
                    dpacc += pv[Mt][rr] * Dv[rr];
                }
            }
            nacc  += __shfl_xor(nacc, 16);  nacc  += __shfl_xor(nacc, 32);
            dpacc += __shfl_xor(dpacc, 16); dpacc += __shfl_xor(dpacc, 32);
            acc[Nt] += dpacc / fmaxf(sqrtf(fmaxf(nacc, 0.f)), 1e-12f);
        }
        __syncthreads();
    }

    // ---- write out ----
    if (quad == 0) {
        const int pr = pxA >> 2, pc = pxA & 3;
        const int l  = (h0 + pr) * WW + (w0 + pc);
        #pragma unroll
        for (int Nt = 0; Nt < 4; ++Nt) {
            const int o = Nt * 16 + lrow;
            out[((size_t)b * OUTC + o) * LPIX + l] = acc[Nt] + dynb[pxA * DBS + o];
        }
    }
}

extern "C" void kernel_launch(void* const* d_in, const int* in_sizes, int n_in,
                              void* d_out, int out_size, void* d_ws, size_t ws_size,
                              hipStream_t stream) {
    const float* x  = (const float*)d_in[0];
    const float* Wp = (const float*)d_in[1];
    const float* bp = (const float*)d_in[2];
    float* out = (float*)d_out;
    (void)in_sizes; (void)n_in; (void)out_size; (void)d_ws; (void)ws_size;

    hipLaunchKernelGGL(dppc9, dim3(BATCH * 288), dim3(512), 0, stream, x, Wp, bp, out);
}